// Round 5
// baseline (277.293 us; speedup 1.0000x reference)
//
#include <hip/hip_runtime.h>

// x: (8, 320, 128, 128) fp32.  C=320 ≡ 0 mod 5  =>  plane%5 == channel%5.
// out(i,j) = (silu(x[s1]) + x[i,j]) * (sigmoid(silu(x[s2])) - 0.5)
// t=c%5: 0: s1=(i,j+1), s2=(i,j+2)   (mod 128)
//        1: s1=(i,j-1), s2=(i,j-2)
//        2: s1=(i+1,j), s2=(i+2,j)
//        3: s1=(i-1,j), s2=(i-2,j)
//        4: s1=s2=(i,j)
//
// Producer-side form: s(p)=silu(x(p)), g(p)=sigmoid(s(p))-0.5 computed once
// per element; out(p) = (s(shift1(p)) + x(p)) * g(shift2(p)). Neighbor s,g
// move bit-exactly via shuffle (W shifts) or an LDS tile (H shifts).
//
// LDS mapping (t=2): idx m <-> plane row row0+m      (rows row0   .. row0+33)
//            (t=3): idx m <-> plane row row0+m-2    (rows row0-2 .. row0+31)
// With this mapping, shift-1 row is lds[li+1] for BOTH t=2 and t=3 (round-4
// bug was using li+3/li+19 for t=3 -> OOB + wrong rows; fixed here).
//
// Round-5: ILP=2 (each thread owns rows r and r+16 of a 32-row tile, both
// loads issued before dependent compute -> 2x bytes in flight). No XCD
// swizzle (regressed +9-10us both times), no NT stores.

#define PLANE_ELEMS 16384   // 128*128

__device__ __forceinline__ float fsig(float z) {
    // 1/(1+exp(-z)) native exp + native rcp; verified absmax 0.015625 (passes).
    return __builtin_amdgcn_rcpf(1.0f + __expf(-z));
}

__global__ __launch_bounds__(512) void ablock_kernel(const float* __restrict__ x,
                                                     float* __restrict__ out,
                                                     int nv4) {
    // 34 rows of s,g per block: 32 owned + 2 halo. 34.8 KB -> 4 blocks/CU,
    // 32 waves/CU (max occupancy).
    __shared__ float4 s_lds[34][32];
    __shared__ float4 g_lds[34][32];

    const int tid   = threadIdx.x;
    const int lane  = tid & 63;
    const int li    = tid >> 5;            // local row 0..15
    const int c4    = tid & 31;            // float4 col within row
    const int plane = blockIdx.x >> 2;     // 4 blocks per plane (32 rows each)
    const int row0  = (blockIdx.x & 3) << 5;  // block's first plane row
    const int t     = plane % 5;           // block-uniform

    const float4* p4 = (const float4*)(x + (size_t)plane * PLANE_ELEMS);
    const int oA = ((row0 + li) << 5) + c4;        // element A: row row0+li
    const int oB = ((row0 + li + 16) << 5) + c4;   // element B: row row0+li+16

    // Issue both owned loads back-to-back (2 outstanding per thread).
    const float4 xA = p4[oA];
    const float4 xB = p4[oB];

    // Issue the halo load before any dependent compute (t=2,3 only).
    const bool hpath = (t == 2) || (t == 3);
    float4 xh;
    int hidx = 0;
    if (hpath && tid < 64) {
        int k   = tid >> 5;                // 0,1
        int hc4 = tid & 31;
        int hrow;
        if (t == 2) { hidx = 32 + k; hrow = (row0 + 32 + k) & 127; }
        else        { hidx = k;      hrow = (row0 - 2 + k) & 127; }
        xh = p4[(hrow << 5) + hc4];
    }

    // Own s,g for both elements (independent chains -> good ILP).
    float4 sA, gA, sB, gB;
    sA.x = xA.x * fsig(xA.x);  sB.x = xB.x * fsig(xB.x);
    sA.y = xA.y * fsig(xA.y);  sB.y = xB.y * fsig(xB.y);
    sA.z = xA.z * fsig(xA.z);  sB.z = xB.z * fsig(xB.z);
    sA.w = xA.w * fsig(xA.w);  sB.w = xB.w * fsig(xB.w);
    gA.x = fsig(sA.x) - 0.5f;  gB.x = fsig(sB.x) - 0.5f;
    gA.y = fsig(sA.y) - 0.5f;  gB.y = fsig(sB.y) - 0.5f;
    gA.z = fsig(sA.z) - 0.5f;  gB.z = fsig(sB.z) - 0.5f;
    gA.w = fsig(sA.w) - 0.5f;  gB.w = fsig(sB.w) - 0.5f;

    float4 rA, rB;

    if (t == 0) {
        // out_j = (s_{j+1} + x_j) * g_{j+2}; need next thread's s.x, g.x, g.y.
        // A row (32 float4) = one half-wave; ring within the half-wave.
        int src = (lane & 32) | ((lane + 1) & 31);
        float snxA = __shfl(sA.x, src, 64), snxB = __shfl(sB.x, src, 64);
        float gnxA = __shfl(gA.x, src, 64), gnxB = __shfl(gB.x, src, 64);
        float gnyA = __shfl(gA.y, src, 64), gnyB = __shfl(gB.y, src, 64);
        rA.x = (sA.y + xA.x) * gA.z;   rB.x = (sB.y + xB.x) * gB.z;
        rA.y = (sA.z + xA.y) * gA.w;   rB.y = (sB.z + xB.y) * gB.w;
        rA.z = (sA.w + xA.z) * gnxA;   rB.z = (sB.w + xB.z) * gnxB;
        rA.w = (snxA + xA.w) * gnyA;   rB.w = (snxB + xB.w) * gnyB;
    } else if (t == 1) {
        // out_j = (s_{j-1} + x_j) * g_{j-2}; need prev thread's s.w, g.z, g.w.
        int src = (lane & 32) | ((lane - 1) & 31);
        float spwA = __shfl(sA.w, src, 64), spwB = __shfl(sB.w, src, 64);
        float gpzA = __shfl(gA.z, src, 64), gpzB = __shfl(gB.z, src, 64);
        float gpwA = __shfl(gA.w, src, 64), gpwB = __shfl(gB.w, src, 64);
        rA.x = (spwA + xA.x) * gpzA;   rB.x = (spwB + xB.x) * gpzB;
        rA.y = (sA.x + xA.y) * gpwA;   rB.y = (sB.x + xB.y) * gpwB;
        rA.z = (sA.y + xA.z) * gA.x;   rB.z = (sB.y + xB.z) * gB.x;
        rA.w = (sA.z + xA.w) * gA.y;   rB.w = (sB.z + xB.w) * gB.y;
    } else if (t == 4) {
        rA.x = (sA.x + xA.x) * gA.x;   rB.x = (sB.x + xB.x) * gB.x;
        rA.y = (sA.y + xA.y) * gA.y;   rB.y = (sB.y + xB.y) * gB.y;
        rA.z = (sA.z + xA.z) * gA.z;   rB.z = (sB.z + xB.z) * gB.z;
        rA.w = (sA.w + xA.w) * gA.w;   rB.w = (sB.w + xB.w) * gB.w;
    } else {
        // Store own rows at the t-dependent base so the mapping above holds.
        const int base = (t == 2) ? li : li + 2;
        s_lds[base][c4]      = sA;  g_lds[base][c4]      = gA;
        s_lds[base + 16][c4] = sB;  g_lds[base + 16][c4] = gB;

        if (tid < 64) {               // halo s,g from the pre-issued load
            int hc4 = tid & 31;
            float4 hs, hg;
            hs.x = xh.x * fsig(xh.x);  hs.y = xh.y * fsig(xh.y);
            hs.z = xh.z * fsig(xh.z);  hs.w = xh.w * fsig(xh.w);
            hg.x = fsig(hs.x) - 0.5f;  hg.y = fsig(hs.y) - 0.5f;
            hg.z = fsig(hs.z) - 0.5f;  hg.w = fsig(hs.w) - 0.5f;
            s_lds[hidx][hc4] = hs;
            g_lds[hidx][hc4] = hg;
        }
        __syncthreads();   // block-uniform branch (t uniform per block)

        // Shift-1 row is lds[li+1] / lds[li+17] for BOTH t=2 and t=3
        // (t=2: row+1 at idx li+1; t=3: row-1 at idx (row-1)-row0+2 = li+1).
        float4 s1A = s_lds[li + 1][c4];
        float4 s1B = s_lds[li + 17][c4];
        float4 g2A, g2B;
        if (t == 2) { g2A = g_lds[li + 2][c4];  g2B = g_lds[li + 18][c4]; }
        else        { g2A = g_lds[li][c4];      g2B = g_lds[li + 16][c4]; }
        rA.x = (s1A.x + xA.x) * g2A.x;   rB.x = (s1B.x + xB.x) * g2B.x;
        rA.y = (s1A.y + xA.y) * g2A.y;   rB.y = (s1B.y + xB.y) * g2B.y;
        rA.z = (s1A.z + xA.z) * g2A.z;   rB.z = (s1B.z + xB.z) * g2B.z;
        rA.w = (s1A.w + xA.w) * g2A.w;   rB.w = (s1B.w + xB.w) * g2B.w;
    }

    float4* o4 = (float4*)out + (size_t)plane * 4096;
    o4[oA] = rA;
    o4[oB] = rB;
}

extern "C" void kernel_launch(void* const* d_in, const int* in_sizes, int n_in,
                              void* d_out, int out_size, void* d_ws, size_t ws_size,
                              hipStream_t stream) {
    const float* x   = (const float*)d_in[0];
    float*       out = (float*)d_out;
    int n   = in_sizes[0];        // 41,943,040
    int nv4 = n >> 2;             // 10,485,760 float4
    int block = 512;              // 32 rows per block, 2 float4 per thread
    int grid  = nv4 / (block * 2);   // 10,240
    ablock_kernel<<<grid, block, 0, stream>>>(x, out, nv4);
}

// Round 6
// 270.229 us; speedup vs baseline: 1.0261x; 1.0261x over previous
//
#include <hip/hip_runtime.h>

// x: (8, 320, 128, 128) fp32.  C=320 ≡ 0 mod 5  =>  plane%5 == channel%5.
// out(i,j) = (silu(x[s1]) + x[i,j]) * (sigmoid(silu(x[s2])) - 0.5)
// t=c%5: 0: s1=(i,j+1), s2=(i,j+2)   (mod 128)
//        1: s1=(i,j-1), s2=(i,j-2)
//        2: s1=(i+1,j), s2=(i+2,j)
//        3: s1=(i-1,j), s2=(i-2,j)
//        4: s1=s2=(i,j)
//
// Producer-side form: s(p)=silu(x(p)), g(p)=sigmoid(s(p))-0.5 computed once
// per element; out(p) = (s(shift1(p)) + x(p)) * g(shift2(p)). Neighbor s,g
// move bit-exactly via shuffle (W shifts) or an LDS tile (H shifts).
//
// FINAL (revert to round-2 best, 63.9us kernel / 269.1us total):
// Tested and rejected across this session (each regressed ~+9-10us kernel):
//  - XCD-aware block swizzle (rounds 1,3): 8 separated DRAM fronts thrash.
//  - Non-temporal stores (round 1).
//  - ILP=2 / 2 loads per thread (round 5): MLP was not the limiter.
// Floor analysis: two disjoint structures (consumer 24-trans, producer
// 16-trans LDS) tie at ~64us = 5.25 TB/s kernel-visible traffic. The timed
// graph's preceding 2x671MB fills leave L3 full of dirty lines; the
// kernel's read misses force concurrent fill writebacks, so true HBM demand
// during the kernel window is ~500+MB ~= 6.5 TB/s = the measured device
// ceiling. The residual 20% gap vs a clean-cache copy is harness-structural,
// not kernel-addressable.

#define PLANE_ELEMS 16384   // 128*128

__device__ __forceinline__ float fsig(float z) {
    // 1/(1+exp(-z)) native exp + native rcp; verified absmax 0.015625 (passes).
    return __builtin_amdgcn_rcpf(1.0f + __expf(-z));
}

__global__ __launch_bounds__(512) void ablock_kernel(const float* __restrict__ x,
                                                     float* __restrict__ out,
                                                     int nv4) {
    // 18 rows of s,g per block: 16 owned + 2 halo. 18.4 KB, not occupancy-binding.
    __shared__ float4 s_lds[18][32];
    __shared__ float4 g_lds[18][32];

    const int tid   = threadIdx.x;
    const int g     = blockIdx.x * 512 + tid;  // float4 index (grid exact)
    const int lane  = tid & 63;
    const int plane = g >> 12;        // 4096 float4 per plane
    const int o     = g & 4095;
    const int li    = tid >> 5;       // local row 0..15 (block = 16 rows)
    const int c4    = tid & 31;       // float4 col within row
    const int row   = o >> 5;         // plane row
    const int t     = plane % 5;      // block-uniform (block = 1/8 plane)

    const float4* p4 = (const float4*)(x + (size_t)plane * PLANE_ELEMS);
    const float4  x0 = p4[o];

    // Own s,g (all paths need exactly these).
    float4 s, gg;
    s.x = x0.x * fsig(x0.x);  s.y = x0.y * fsig(x0.y);
    s.z = x0.z * fsig(x0.z);  s.w = x0.w * fsig(x0.w);
    gg.x = fsig(s.x) - 0.5f;  gg.y = fsig(s.y) - 0.5f;
    gg.z = fsig(s.z) - 0.5f;  gg.w = fsig(s.w) - 0.5f;

    float4 r;

    if (t == 0) {
        // out_j = (s_{j+1} + x_j) * g_{j+2}; need next thread's s.x, g.x, g.y.
        // Row = 32 float4 = one half-wave; ring within half-wave.
        int src = (lane & 32) | ((lane + 1) & 31);
        float snx = __shfl(s.x,  src, 64);
        float gnx = __shfl(gg.x, src, 64);
        float gny = __shfl(gg.y, src, 64);
        r.x = (s.y + x0.x) * gg.z;
        r.y = (s.z + x0.y) * gg.w;
        r.z = (s.w + x0.z) * gnx;
        r.w = (snx + x0.w) * gny;
    } else if (t == 1) {
        // out_j = (s_{j-1} + x_j) * g_{j-2}; need prev thread's s.w, g.z, g.w.
        int src = (lane & 32) | ((lane - 1) & 31);
        float spw = __shfl(s.w,  src, 64);
        float gpz = __shfl(gg.z, src, 64);
        float gpw = __shfl(gg.w, src, 64);
        r.x = (spw + x0.x) * gpz;
        r.y = (s.x + x0.y) * gpw;
        r.z = (s.y + x0.z) * gg.x;
        r.w = (s.z + x0.w) * gg.y;
    } else if (t == 4) {
        r.x = (s.x + x0.x) * gg.x;
        r.y = (s.y + x0.y) * gg.y;
        r.z = (s.z + x0.z) * gg.z;
        r.w = (s.w + x0.w) * gg.w;
    } else {
        // t==2: out(i) = (s(i+1)+x(i))*g(i+2); LDS idx m <-> plane row row0+m.
        // t==3: out(i) = (s(i-1)+x(i))*g(i-2); LDS idx m <-> plane row row0+m-2.
        const int base = (t == 2) ? li : li + 2;
        s_lds[base][c4] = s;
        g_lds[base][c4] = gg;

        // Halo: wave 0 computes s,g for the 2 rows beyond the owned 16.
        if (tid < 64) {
            int k    = tid >> 5;      // 0,1
            int hc4  = tid & 31;
            int row0 = row - li;      // block's first plane row
            int hidx, hrow;
            if (t == 2) { hidx = 16 + k; hrow = (row0 + 16 + k) & 127; }
            else        { hidx = k;      hrow = (row0 - 2 + k) & 127; }
            float4 xh = p4[(hrow << 5) + hc4];
            float4 hs, hg;
            hs.x = xh.x * fsig(xh.x);  hs.y = xh.y * fsig(xh.y);
            hs.z = xh.z * fsig(xh.z);  hs.w = xh.w * fsig(xh.w);
            hg.x = fsig(hs.x) - 0.5f;  hg.y = fsig(hs.y) - 0.5f;
            hg.z = fsig(hs.z) - 0.5f;  hg.w = fsig(hs.w) - 0.5f;
            s_lds[hidx][hc4] = hs;
            g_lds[hidx][hc4] = hg;
        }
        __syncthreads();   // block-uniform branch (t uniform per block)

        float4 s1 = s_lds[li + 1][c4];   // shift-1 row (both t=2 and t=3)
        float4 g2;
        if (t == 2) g2 = g_lds[li + 2][c4];
        else        g2 = g_lds[li][c4];
        r.x = (s1.x + x0.x) * g2.x;
        r.y = (s1.y + x0.y) * g2.y;
        r.z = (s1.z + x0.z) * g2.z;
        r.w = (s1.w + x0.w) * g2.w;
    }

    ((float4*)out)[g] = r;
}

extern "C" void kernel_launch(void* const* d_in, const int* in_sizes, int n_in,
                              void* d_out, int out_size, void* d_ws, size_t ws_size,
                              hipStream_t stream) {
    const float* x   = (const float*)d_in[0];
    float*       out = (float*)d_out;
    int n   = in_sizes[0];        // 41,943,040
    int nv4 = n >> 2;             // 10,485,760 float4
    int block = 512;              // 16 rows per block (LDS tile for H shifts)
    int grid  = nv4 / block;      // 20,480 (exact)
    ablock_kernel<<<grid, block, 0, stream>>>(x, out, nv4);
}